// Round 5
// baseline (1295.705 us; speedup 1.0000x reference)
//
#include <hip/hip_runtime.h>
#include <stdint.h>

#define OUTF 11008
#define INF  4096
#define NG   32      // groups = INF/128
#define TOK  8192
#define KB4  2048    // int32 per qweight row = INF/2

// ---- main GEMM geometry: 256x256 tile, 8 waves, m201 8-phase template ----
#define BM 256
#define BN 256
#define BK 64
#define NT (INF / BK)    // 64 K-tiles
#define GX (OUTF / BN)   // 43
#define GY (TOK / BM)    // 32
#define NWG (GX * GY)    // 1376, % 8 == 0 -> simple bijective XCD swizzle

typedef unsigned short u16;
typedef __attribute__((ext_vector_type(8))) short bf16x8;
typedef __attribute__((ext_vector_type(4))) float f32x4;

// fp32 -> bf16 round-to-nearest-even (inputs finite)
__device__ inline u16 f2bf(float f) {
  union { float f; uint32_t u; } v; v.f = f;
  return (u16)((v.u + 0x7fff + ((v.u >> 16) & 1)) >> 16);
}

// async global->LDS, 16B per lane; lds dest must be wave-uniform base (+lane*16 implicit)
__device__ inline void async_copy16(const void* g, const void* l) {
  __builtin_amdgcn_global_load_lds(
      (__attribute__((address_space(1))) void*)(g),
      (__attribute__((address_space(3))) void*)(l), 16, 0, 0);
}

#define FENCE() asm volatile("" ::: "memory")
#define BAR()   do { FENCE(); __builtin_amdgcn_s_barrier(); FENCE(); } while (0)
#define VMCNT(n) asm volatile("s_waitcnt vmcnt(" #n ")" ::: "memory")

// ---------------- fused preprocessing kernel (unchanged) ----------------

#define NXU ((long long)TOK * INF / 4)    // 8,388,608
#define NWU ((long long)OUTF * KB4 / 4)   // 5,636,096
#define PREPBLK 2048

__global__ __launch_bounds__(256) void prep(const float* __restrict__ X,
                                            const int* __restrict__ QW,
                                            const float* __restrict__ scales,
                                            const float* __restrict__ zeros,
                                            u16* __restrict__ Xb,
                                            u16* __restrict__ Wb) {
  const long long stride = (long long)gridDim.x * 256;
  for (long long i = (long long)blockIdx.x * 256 + threadIdx.x; i < NXU + NWU;
       i += stride) {
    if (i < NXU) {
      const float4 f = ((const float4*)X)[i];
      union { u16 t[4]; uint2 v; } u;
      u.t[0] = f2bf(f.x); u.t[1] = f2bf(f.y);
      u.t[2] = f2bf(f.z); u.t[3] = f2bf(f.w);
      ((uint2*)Xb)[i] = u.v;
    } else {
      const long long j = i - NXU;          // w-unit: 4 ints of row o
      const int o = (int)(j >> 9);          // 512 units per row (2048/4)
      const int c0 = ((int)j & 511) * 4;    // int column; group = c0/64 (4 | 64)
      const int g = c0 >> 6;
      const float s = scales[o * NG + g];
      const float zs = -zeros[o * NG + g] * s;
      const int4 q = ((const int4*)QW)[j];
      const int qq[4] = {q.x, q.y, q.z, q.w};
      union { u16 t[8]; int4 v; } u;
#pragma unroll
      for (int k = 0; k < 4; ++k) {
        u.t[2 * k]     = f2bf(fmaf((float)(qq[k] & 15), s, zs));
        u.t[2 * k + 1] = f2bf(fmaf((float)((qq[k] >> 4) & 15), s, zs));
      }
      ((int4*)Wb)[j] = u.v;                 // bf16 cols [2*c0, 2*c0+8)
    }
  }
}

// ---------------- main GEMM: m201-faithful 8-phase, 2 K-tiles/iter ----------------
// LDS XOR-swizzle: 16B granule g of local row r at g ^ (r&7), pre-swizzled
// GLOBAL source + linear LDS dest (measured conflict-free: counter = 0).
// A-frag: A[m=lane&15][k=(lane>>4)*8+j]; C/D: col=lane&15, row=(lane>>4)*4+reg.
//
// Iteration = 2 K-tiles: tile t in slot0 (phases 0-3), tile t+1 in slot1
// (phases 4-7). Phase = (slot, ks, mh); each phase:
//   { ds_read this phase's frags (A:4, +B:4 on mh0 phases)
//     2 x global_load_lds  (exactly ONE half-tile -- the m196 fine-interleave)
//     [VMCNT(2) in ph3/ph7 only -- certify-one-phase-early, never 0 mid-loop]
//     s_barrier | setprio(1) 16 MFMA setprio(0) | s_barrier }
// No explicit lgkm drain: compiler emits fine-grained lgkmcnt(N) so early
// MFMAs overlap the tail of the read drain; MFMA pipe drains past the end
// barrier into the next phase's read region.
//
// Region liveness (reads of phase p complete before p's MFMA via lgkm wait,
// hence before p's end-barrier for ALL waves -> stage at p+1 is race-free):
//   slot1.B      read ph4,ph6  -> stage T+1 copy at ph0,ph1 (prev certify ph6)
//   slot1.A mh1  read ph5,ph7  -> stage T+1 copy at ph2
//   slot0.A mh0  read ph0,ph2  -> stage T+2 copy at ph3
//   slot0.B      read ph0,ph2  -> stage T+2 copy at ph4,ph5
//   slot0.A mh1  read ph1,ph3  -> stage T+2 copy at ph6
//   slot1.A mh0  read ph4,ph6  -> stage T+3 copy at ph7
// vmcnt accounting (2 loads/phase, FIFO):
//   ph3 (after its stage): outstanding = ph7prev,ph0,ph1,ph2,ph3 = 10;
//     VMCNT(2) drains oldest 8 = everything tile T+1 needs, before ph4 reads.
//   ph7 (after its stage): outstanding = ph3..ph7 = 10; VMCNT(2) drains
//     ph3-ph6 = everything tile T+2 needs, before next-iter ph0 reads.

__global__ __launch_bounds__(512, 2) void gemm_pre512(const u16* __restrict__ A,
                                                      const u16* __restrict__ B,
                                                      const float* __restrict__ bias,
                                                      float* __restrict__ C) {
  __shared__ __align__(16) u16 As[2][BM * BK];   // 2 x 32 KB
  __shared__ __align__(16) u16 Bs[2][BN * BK];   // 2 x 32 KB  (total 128 KB)
  const int tid = threadIdx.x;
  const int lane = tid & 63;
  const int wid = __builtin_amdgcn_readfirstlane(tid >> 6);

  // XCD-aware bijective block swizzle (NWG % 8 == 0)
  const int lin = blockIdx.x;
  const int wg = (lin & 7) * (NWG / 8) + (lin >> 3);
  const int bm = wg / GX;
  const int bn = wg % GX;

  const u16* Ab = A + (size_t)bm * BM * INF;
  const u16* Bb = B + (size_t)bn * BN * INF;

  // staging addressing: one global_load_lds (all 8 waves) covers 64 rows
  const int rowoff = tid >> 3;                    // 0..63
  const int gran = (tid & 7) ^ (rowoff & 7);      // pre-swizzled source granule
  const u16* Asrc = Ab + (size_t)rowoff * INF + gran * 8;
  const u16* Bsrc = Bb + (size_t)rowoff * INF + gran * 8;
  const int wid8 = wid * 8;

  // frag addressing
  const int rr = lane & 15;
  const int q4 = lane >> 4;
  const int wm = wid >> 2;   // 0..1 -> 128-row half of A tile
  const int wn = wid & 3;    // 0..3 -> 64-row quarter of B tile

  f32x4 acc[8][4] = {};
  bf16x8 bq[4];              // B frags for current ks (live across 2 phases)

// single 64-row staging call (1 VMEM instr/wave; wave w covers rows R0+8w..+7)
#define STAGE1(LDS, SRC, TT, R0)                                               \
  async_copy16((SRC) + (size_t)(R0) * INF + (size_t)(TT) * BK,                 \
               (const char*)(LDS) + ((R0) + wid8) * 128);

// 4 ds_read_b128: one A quadrant-row set (fixed ks, fixed mh)
#define RD_A4(DST, S, KS, MH)                                                  \
  _Pragma("unroll") for (int mi = 0; mi < 4; ++mi)                             \
    DST[mi] = *(const bf16x8*)&As[S][                                          \
        (wm * 128 + (MH) * 64 + mi * 16 + rr) * BK +                           \
        ((((KS) * 4 + q4) ^ (rr & 7)) * 8)];

// 4 ds_read_b128: B frags for fixed ks
#define RD_B4(DST, S, KS)                                                      \
  _Pragma("unroll") for (int ni = 0; ni < 4; ++ni)                             \
    DST[ni] = *(const bf16x8*)&Bs[S][                                          \
        (wn * 64 + ni * 16 + rr) * BK +                                        \
        ((((KS) * 4 + q4) ^ (rr & 7)) * 8)];

#define MFMA16(RA, RB, MH)                                                     \
  do {                                                                         \
    __builtin_amdgcn_s_setprio(1);                                             \
    _Pragma("unroll") for (int mi = 0; mi < 4; ++mi)                           \
      _Pragma("unroll") for (int ni = 0; ni < 4; ++ni)                         \
        acc[(MH) * 4 + mi][ni] = __builtin_amdgcn_mfma_f32_16x16x32_bf16(      \
            RA[mi], RB[ni], acc[(MH) * 4 + mi][ni], 0, 0, 0);                  \
    __builtin_amdgcn_s_setprio(0);                                             \
  } while (0)

  // prologue: T0 full (8 loads) -> slot0; A1.mh0 (2 loads) -> slot1.
  // VMCNT(2) drains the oldest 8 (= all of T0); steady state from iter 0.
  STAGE1(&As[0][0], Asrc, 0, 0)   STAGE1(&As[0][0], Asrc, 0, 128)   // A0 mh0
  STAGE1(&As[0][0], Asrc, 0, 64)  STAGE1(&As[0][0], Asrc, 0, 192)   // A0 mh1
  STAGE1(&Bs[0][0], Bsrc, 0, 0)   STAGE1(&Bs[0][0], Bsrc, 0, 64)    // B0 h0
  STAGE1(&Bs[0][0], Bsrc, 0, 128) STAGE1(&Bs[0][0], Bsrc, 0, 192)   // B0 h1
  STAGE1(&As[1][0], Asrc, 1, 0)   STAGE1(&As[1][0], Asrc, 1, 128)   // A1 mh0
  VMCNT(2);
  BAR();

  for (int t = 0; t < NT; t += 2) {
    // ph0: slot0 (ks0,mh0) | stage B1.h0 (T+1)
    {
      bf16x8 ra[4];
      RD_A4(ra, 0, 0, 0) RD_B4(bq, 0, 0)
      STAGE1(&Bs[1][0], Bsrc, t + 1, 0) STAGE1(&Bs[1][0], Bsrc, t + 1, 64)
      BAR(); MFMA16(ra, bq, 0); BAR();
    }
    // ph1: slot0 (ks0,mh1) | stage B1.h1 (T+1)
    {
      bf16x8 ra[4];
      RD_A4(ra, 0, 0, 1)
      STAGE1(&Bs[1][0], Bsrc, t + 1, 128) STAGE1(&Bs[1][0], Bsrc, t + 1, 192)
      BAR(); MFMA16(ra, bq, 1); BAR();
    }
    // ph2: slot0 (ks1,mh0) | stage A1.mh1 (T+1)
    {
      bf16x8 ra[4];
      RD_A4(ra, 0, 1, 0) RD_B4(bq, 0, 1)
      STAGE1(&As[1][0], Asrc, t + 1, 64) STAGE1(&As[1][0], Asrc, t + 1, 192)
      BAR(); MFMA16(ra, bq, 0); BAR();
    }
    // ph3: slot0 (ks1,mh1) | stage A0.mh0 (T+2) | VMCNT(2): certify T+1
    {
      bf16x8 ra[4];
      RD_A4(ra, 0, 1, 1)
      if (t + 2 < NT) {
        STAGE1(&As[0][0], Asrc, t + 2, 0) STAGE1(&As[0][0], Asrc, t + 2, 128)
        VMCNT(2);
      } else {
        VMCNT(0);
      }
      BAR(); MFMA16(ra, bq, 1); BAR();
    }
    // ph4: slot1 (ks0,mh0) | stage B0.h0 (T+2)
    {
      bf16x8 ra[4];
      RD_A4(ra, 1, 0, 0) RD_B4(bq, 1, 0)
      if (t + 2 < NT) {
        STAGE1(&Bs[0][0], Bsrc, t + 2, 0) STAGE1(&Bs[0][0], Bsrc, t + 2, 64)
      }
      BAR(); MFMA16(ra, bq, 0); BAR();
    }
    // ph5: slot1 (ks0,mh1) | stage B0.h1 (T+2)
    {
      bf16x8 ra[4];
      RD_A4(ra, 1, 0, 1)
      if (t + 2 < NT) {
        STAGE1(&Bs[0][0], Bsrc, t + 2, 128) STAGE1(&Bs[0][0], Bsrc, t + 2, 192)
      }
      BAR(); MFMA16(ra, bq, 1); BAR();
    }
    // ph6: slot1 (ks1,mh0) | stage A0.mh1 (T+2)
    {
      bf16x8 ra[4];
      RD_A4(ra, 1, 1, 0) RD_B4(bq, 1, 1)
      if (t + 2 < NT) {
        STAGE1(&As[0][0], Asrc, t + 2, 64) STAGE1(&As[0][0], Asrc, t + 2, 192)
      }
      BAR(); MFMA16(ra, bq, 0); BAR();
    }
    // ph7: slot1 (ks1,mh1) | stage A1.mh0 (T+3) | VMCNT(2): certify T+2
    {
      bf16x8 ra[4];
      RD_A4(ra, 1, 1, 1)
      if (t + 3 < NT) {
        STAGE1(&As[1][0], Asrc, t + 3, 0) STAGE1(&As[1][0], Asrc, t + 3, 128)
        VMCNT(2);
      } else {
        VMCNT(0);
      }
      BAR(); MFMA16(ra, bq, 1); BAR();
    }
  }

  // epilogue
  const int ncol = lane & 15;
  const int qrow = (lane >> 4) * 4;
  float bv[4];
#pragma unroll
  for (int ni = 0; ni < 4; ++ni)
    bv[ni] = bias[bn * BN + wn * 64 + ni * 16 + ncol];
#pragma unroll
  for (int mi = 0; mi < 8; ++mi)
#pragma unroll
    for (int ni = 0; ni < 4; ++ni) {
      const int gn = bn * BN + wn * 64 + ni * 16 + ncol;
#pragma unroll
      for (int r = 0; r < 4; ++r) {
        const int gm = bm * BM + wm * 128 + mi * 16 + qrow + r;
        C[(size_t)gm * OUTF + gn] = acc[mi][ni][r] + bv[ni];
      }
    }
}

// ---------------- fused fallback (no workspace requirement) ----------------

#define FBM 128
#define FBN 128

#define FMFMA_COMPUTE()                                                       \
  do {                                                                        \
    const int frr = lane & 15;                                                \
    const int fq4 = lane >> 4;                                                \
    _Pragma("unroll") for (int ks = 0; ks < 2; ++ks) {                        \
      bf16x8 fa[4], fb[4];                                                    \
      const int kk = (((ks * 4 + fq4) ^ (frr & 7)) * 8);                      \
      _Pragma("unroll") for (int i = 0; i < 4; ++i) {                         \
        fa[i] = *(const bf16x8*)&Asf[(mwave + i * 16 + frr) * BK + kk];       \
        fb[i] = *(const bf16x8*)&Bsf[(nwave + i * 16 + frr) * BK + kk];       \
      }                                                                       \
      _Pragma("unroll") for (int mi = 0; mi < 4; ++mi)                        \
        _Pragma("unroll") for (int ni = 0; ni < 4; ++ni)                      \
          facc[mi][ni] = __builtin_amdgcn_mfma_f32_16x16x32_bf16(             \
              fa[mi], fb[ni], facc[mi][ni], 0, 0, 0);                         \
    }                                                                         \
  } while (0)

__global__ __launch_bounds__(256) void gemm_fused(const float* __restrict__ X,
                                                  const int* __restrict__ QW,
                                                  const float* __restrict__ scales,
                                                  const float* __restrict__ zeros,
                                                  const float* __restrict__ bias,
                                                  float* __restrict__ C) {
  __shared__ __align__(16) u16 Asf[FBM * BK];
  __shared__ __align__(16) u16 Bsf[FBN * BK];
  const int tid = threadIdx.x;
  const int lane = tid & 63;
  const int wid = tid >> 6;
  const int bm = blockIdx.y, bn = blockIdx.x;
  const int row = tid >> 1;
  const int half = tid & 1;
  const float* xr = X + (size_t)(bm * FBM + row) * INF + half * 32;
  const int* qr = QW + (size_t)(bn * FBN + row) * KB4 + half * 16;
  const float* srow = scales + (size_t)(bn * FBN + row) * NG;
  const float* zrow = zeros + (size_t)(bn * FBN + row) * NG;
  const int mwave = (wid >> 1) * 64;
  const int nwave = (wid & 1) * 64;
  f32x4 facc[4][4] = {};

  for (int kb = 0; kb < INF / BK; ++kb) {
    const int k0 = kb * BK;
    union { u16 t[32]; int4 v[4]; } ta, tb;
#pragma unroll
    for (int j = 0; j < 8; ++j) {
      const float4 f = *(const float4*)(xr + k0 + j * 4);
      ta.t[4 * j]     = f2bf(f.x);
      ta.t[4 * j + 1] = f2bf(f.y);
      ta.t[4 * j + 2] = f2bf(f.z);
      ta.t[4 * j + 3] = f2bf(f.w);
    }
    {
      const float s = srow[kb >> 1];
      const float zs = -zrow[kb >> 1] * s;
#pragma unroll
      for (int j = 0; j < 4; ++j) {
        const int4 q = *(const int4*)(qr + kb * 32 + j * 4);
        const int qq[4] = {q.x, q.y, q.z, q.w};
#pragma unroll
        for (int u = 0; u < 4; ++u) {
          tb.t[8 * j + 2 * u]     = f2bf(fmaf((float)(qq[u] & 15), s, zs));
          tb.t[8 * j + 2 * u + 1] = f2bf(fmaf((float)((qq[u] >> 4) & 15), s, zs));
        }
      }
    }
    __syncthreads();
#pragma unroll
    for (int j = 0; j < 4; ++j) {
      *(int4*)&Asf[row * BK + (((half * 4 + j) ^ (row & 7)) * 8)] = ta.v[j];
      *(int4*)&Bsf[row * BK + (((half * 4 + j) ^ (row & 7)) * 8)] = tb.v[j];
    }
    __syncthreads();
    FMFMA_COMPUTE();
  }
  {
    const int ncol = lane & 15;
    const int qrow = (lane >> 4) * 4;
#pragma unroll
    for (int mi = 0; mi < 4; ++mi)
#pragma unroll
      for (int ni = 0; ni < 4; ++ni) {
        const int gn = bn * FBN + nwave + ni * 16 + ncol;
        const float bvv = bias[gn];
#pragma unroll
        for (int r = 0; r < 4; ++r) {
          const int gm = bm * FBM + mwave + mi * 16 + qrow + r;
          C[(size_t)gm * OUTF + gn] = facc[mi][ni][r] + bvv;
        }
      }
  }
}

// ---------------- launch ----------------

extern "C" void kernel_launch(void* const* d_in, const int* in_sizes, int n_in,
                              void* d_out, int out_size, void* d_ws, size_t ws_size,
                              hipStream_t stream) {
  const float* x = (const float*)d_in[0];
  const int* qw = (const int*)d_in[1];
  const float* scales = (const float*)d_in[2];
  const float* zeros = (const float*)d_in[3];
  const float* bias = (const float*)d_in[4];
  float* out = (float*)d_out;

  const size_t needW = (size_t)OUTF * INF * sizeof(u16);  // 90,177,536 B
  const size_t needX = (size_t)TOK * INF * sizeof(u16);   // 67,108,864 B

  if (ws_size >= needW + needX) {
    u16* Wb = (u16*)d_ws;
    u16* Xb = (u16*)((char*)d_ws + needW);
    prep<<<PREPBLK, 256, 0, stream>>>(x, qw, scales, zeros, Xb, Wb);
    gemm_pre512<<<dim3(NWG), 512, 0, stream>>>(Xb, Wb, bias, out);
  } else {
    gemm_fused<<<dim3(OUTF / FBN, TOK / FBM), 256, 0, stream>>>(x, qw, scales, zeros, bias, out);
  }
}

// Round 6
// 1101.592 us; speedup vs baseline: 1.1762x; 1.1762x over previous
//
#include <hip/hip_runtime.h>
#include <stdint.h>

#define OUTF 11008
#define INF  4096
#define NG   32      // groups = INF/128
#define TOK  8192
#define KB4  2048    // int32 per qweight row = INF/2

// ---- main GEMM geometry: 256x256 tile, 8 waves, 8-phase deep-prefetch ----
#define BM 256
#define BN 256
#define BK 64
#define NT (INF / BK)    // 64 K-tiles
#define GX (OUTF / BN)   // 43
#define GY (TOK / BM)    // 32
#define NWG (GX * GY)    // 1376 = 8 XCD chunks x 172

typedef unsigned short u16;
typedef __attribute__((ext_vector_type(8))) short bf16x8;
typedef __attribute__((ext_vector_type(4))) float f32x4;
typedef __attribute__((ext_vector_type(4))) int i32x4;

// fp32 -> bf16 round-to-nearest-even (inputs finite)
__device__ inline u16 f2bf(float f) {
  union { float f; uint32_t u; } v; v.f = f;
  return (u16)((v.u + 0x7fff + ((v.u >> 16) & 1)) >> 16);
}

// async global->LDS, 16B per lane; lds dest must be wave-uniform base (+lane*16 implicit)
__device__ inline void async_copy16(const void* g, const void* l) {
  __builtin_amdgcn_global_load_lds(
      (__attribute__((address_space(1))) void*)(g),
      (__attribute__((address_space(3))) void*)(l), 16, 0, 0);
}

#define FENCE() asm volatile("" ::: "memory")
#define BAR()   do { FENCE(); __builtin_amdgcn_s_barrier(); FENCE(); } while (0)
#define VMCNT(n) asm volatile("s_waitcnt vmcnt(" #n ")" ::: "memory")

// ---------------- fused preprocessing kernel ----------------
// NT loads on the once-read fp32/packed inputs (don't pollute L3 -- the bf16
// outputs Xb/Wb are the panels gemm will re-read 5-12x and must stay cached).

#define NXU ((long long)TOK * INF / 4)    // 8,388,608
#define NWU ((long long)OUTF * KB4 / 4)   // 5,636,096
#define PREPBLK 2048

__global__ __launch_bounds__(256) void prep(const float* __restrict__ X,
                                            const int* __restrict__ QW,
                                            const float* __restrict__ scales,
                                            const float* __restrict__ zeros,
                                            u16* __restrict__ Xb,
                                            u16* __restrict__ Wb) {
  const long long stride = (long long)gridDim.x * 256;
  for (long long i = (long long)blockIdx.x * 256 + threadIdx.x; i < NXU + NWU;
       i += stride) {
    if (i < NXU) {
      const f32x4 f = __builtin_nontemporal_load((const f32x4*)X + i);
      union { u16 t[4]; uint2 v; } u;
      u.t[0] = f2bf(f[0]); u.t[1] = f2bf(f[1]);
      u.t[2] = f2bf(f[2]); u.t[3] = f2bf(f[3]);
      ((uint2*)Xb)[i] = u.v;
    } else {
      const long long j = i - NXU;          // w-unit: 4 ints of row o
      const int o = (int)(j >> 9);          // 512 units per row (2048/4)
      const int c0 = ((int)j & 511) * 4;    // int column; group = c0/64 (4 | 64)
      const int g = c0 >> 6;
      const float s = scales[o * NG + g];
      const float zs = -zeros[o * NG + g] * s;
      const i32x4 q = __builtin_nontemporal_load((const i32x4*)QW + j);
      union { u16 t[8]; int4 v; } u;
#pragma unroll
      for (int k = 0; k < 4; ++k) {
        u.t[2 * k]     = f2bf(fmaf((float)(q[k] & 15), s, zs));
        u.t[2 * k + 1] = f2bf(fmaf((float)((q[k] >> 4) & 15), s, zs));
      }
      ((int4*)Wb)[j] = u.v;                 // bf16 cols [2*c0, 2*c0+8)
    }
  }
}

// ---------------- main GEMM: 8-phase, deep prefetch, shallow counted waits ----
// LDS XOR-swizzle: 16B granule g of local row r at g ^ (r&7) (conflict-free,
// counter-verified 0), via pre-swizzled GLOBAL source + linear LDS dest.
// A-frag: A[m=lane&15][k=(lane>>4)*8+j]; C/D: col=lane&15, row=(lane>>4)*4+reg.
//
// Regions (2 global_load_lds each): A.mh0={r0:0,128} A.mh1={64,192}
// B.h0={0,64} B.h1={128,192}. Reads: ph0{A0mh0,B0 all} ph1{A0mh1} ph2{A0mh0,B0}
// ph3{A0mh1} ph4-7 same on slot1. Last collective read: A0mh0/B0@ph2,
// A0mh1@ph3, A1mh0/B1@ph6, A1mh1@ph7 (certified by that phase's END barrier).
//
// Stage schedule (2 loads/phase, every region staged 3-5 phases before first
// read; freed-check = stage phase > last-read phase of old data, all pass):
//   ph0: B1.h1(t+1)  ph1: A1.mh0(t+1)  ph2: A1.mh1(t+1)  ph3: B0.h0(t+2)
//   ph4: B0.h1(t+2)  ph5: A0.mh0(t+2)  ph6: A0.mh1(t+2)  ph7: B1.h0(t+3)
// Waits (AFTER the MFMA cluster -- matrix pipe runs during the drain; END
// barrier makes them collective before the next phase's reads). Outstanding
// audit (2 per stage, FIFO):
//   ph0 VMCNT(4): out={pf6:A0mh1(t), pf7:B1h0(t+1), ph0}=6 -> drains A0mh1(t)
//       (needed ph1); waited loads ~2 phases old.
//   ph3 VMCNT(4): out={pf7,ph0,ph1,ph2,ph3}=10 -> drains B1h0,B1h1,A1mh0
//       (needed ph4); >=2 phases old.
//   ph4 VMCNT(4): out={ph2,ph3,ph4}=6 -> drains A1mh1 (needed ph5).
//   ph7 VMCNT(4): out={ph3..ph7}=10 -> drains B0h0,B0h1,A0mh0 (needed ph0').
// Tail (t+2>=NT): stages skipped, VMCNT(0) at ph3/ph4/ph7 drains everything.

__global__ __launch_bounds__(512, 2) void gemm_pre512(const u16* __restrict__ A,
                                                      const u16* __restrict__ B,
                                                      const float* __restrict__ bias,
                                                      float* __restrict__ C) {
  __shared__ __align__(16) u16 As[2][BM * BK];   // 2 x 32 KB
  __shared__ __align__(16) u16 Bs[2][BN * BK];   // 2 x 32 KB  (total 128 KB)
  const int tid = threadIdx.x;
  const int lane = tid & 63;
  const int wid = __builtin_amdgcn_readfirstlane(tid >> 6);

  // XCD-local 2D grouping: XCD k (= lin&7, round-robin dispatch heuristic)
  // owns bm in [4k,4k+4); within the 172-wg chunk, blocks walk 4bm x 8bn
  // rectangles (32 wgs = 1 CU-fill) -> concurrent set = 4 A-panels (8 MB,
  // XCD-resident for the whole run) + 8 B-panels (16 MB, 4-way L2 reuse).
  const int lin = blockIdx.x;
  const int xcd = lin & 7;
  const int wgc = lin >> 3;                 // 0..171
  int bmr, bn;
  if (wgc < 160) {
    const int g = wgc >> 5, r = wgc & 31;
    bn = g * 8 + (r & 7);
    bmr = r >> 3;
  } else {
    const int r = wgc - 160;
    bn = 40 + r % 3;
    bmr = r / 3;
  }
  const int bm = xcd * 4 + bmr;

  const u16* Ab = A + (size_t)bm * BM * INF;
  const u16* Bb = B + (size_t)bn * BN * INF;

  // staging addressing: one global_load_lds (all 8 waves) covers 64 rows
  const int rowoff = tid >> 3;                    // 0..63
  const int gran = (tid & 7) ^ (rowoff & 7);      // pre-swizzled source granule
  const u16* Asrc = Ab + (size_t)rowoff * INF + gran * 8;
  const u16* Bsrc = Bb + (size_t)rowoff * INF + gran * 8;
  const int wid8 = wid * 8;

  // frag addressing
  const int rr = lane & 15;
  const int q4 = lane >> 4;
  const int wm = wid >> 2;   // 0..1 -> 128-row half of A tile
  const int wn = wid & 3;    // 0..3 -> 64-row quarter of B tile

  f32x4 acc[8][4] = {};
  bf16x8 bq[4];              // B frags for current ks (live across 2 phases)

// single 64-row staging call (1 VMEM instr/wave; wave w covers rows R0+8w..+7)
#define STAGE1(LDS, SRC, TT, R0)                                               \
  async_copy16((SRC) + (size_t)(R0) * INF + (size_t)(TT) * BK,                 \
               (const char*)(LDS) + ((R0) + wid8) * 128);

// 4 ds_read_b128: one A quadrant-row set (fixed ks, fixed mh)
#define RD_A4(DST, S, KS, MH)                                                  \
  _Pragma("unroll") for (int mi = 0; mi < 4; ++mi)                             \
    DST[mi] = *(const bf16x8*)&As[S][                                          \
        (wm * 128 + (MH) * 64 + mi * 16 + rr) * BK +                           \
        ((((KS) * 4 + q4) ^ (rr & 7)) * 8)];

// 4 ds_read_b128: B frags for fixed ks
#define RD_B4(DST, S, KS)                                                      \
  _Pragma("unroll") for (int ni = 0; ni < 4; ++ni)                             \
    DST[ni] = *(const bf16x8*)&Bs[S][                                          \
        (wn * 64 + ni * 16 + rr) * BK +                                        \
        ((((KS) * 4 + q4) ^ (rr & 7)) * 8)];

#define MFMA16(RA, RB, MH)                                                     \
  do {                                                                         \
    __builtin_amdgcn_s_setprio(1);                                             \
    _Pragma("unroll") for (int mi = 0; mi < 4; ++mi)                           \
      _Pragma("unroll") for (int ni = 0; ni < 4; ++ni)                         \
        acc[(MH) * 4 + mi][ni] = __builtin_amdgcn_mfma_f32_16x16x32_bf16(      \
            RA[mi], RB[ni], acc[(MH) * 4 + mi][ni], 0, 0, 0);                  \
    __builtin_amdgcn_s_setprio(0);                                             \
  } while (0)

  // prologue issue order (plays the steady-state tail of a virtual prev iter):
  //  [1-3] A0.mh0(0), B0.h0(0), B0.h1(0)  -- needed by ph0
  //  [4]   A0.mh1(0)                      -- "prev ph6", needed by ph1
  //  [5]   B1.h0(1)                       -- "prev ph7", needed by ph4
  // VMCNT(4) drains [1-3]; [4],[5] stay in flight (steady-state entry).
  STAGE1(&As[0][0], Asrc, 0, 0)   STAGE1(&As[0][0], Asrc, 0, 128)
  STAGE1(&Bs[0][0], Bsrc, 0, 0)   STAGE1(&Bs[0][0], Bsrc, 0, 64)
  STAGE1(&Bs[0][0], Bsrc, 0, 128) STAGE1(&Bs[0][0], Bsrc, 0, 192)
  STAGE1(&As[0][0], Asrc, 0, 64)  STAGE1(&As[0][0], Asrc, 0, 192)
  STAGE1(&Bs[1][0], Bsrc, 1, 0)   STAGE1(&Bs[1][0], Bsrc, 1, 64)
  VMCNT(4);
  BAR();

  for (int t = 0; t < NT; t += 2) {
    // ph0: slot0 (ks0,mh0) | stage B1.h1(t+1) | VMCNT(4) post-MFMA
    {
      bf16x8 ra[4];
      RD_A4(ra, 0, 0, 0) RD_B4(bq, 0, 0)
      STAGE1(&Bs[1][0], Bsrc, t + 1, 128) STAGE1(&Bs[1][0], Bsrc, t + 1, 192)
      BAR(); MFMA16(ra, bq, 0);
      VMCNT(4);
      BAR();
    }
    // ph1: slot0 (ks0,mh1) | stage A1.mh0(t+1)
    {
      bf16x8 ra[4];
      RD_A4(ra, 0, 0, 1)
      STAGE1(&As[1][0], Asrc, t + 1, 0) STAGE1(&As[1][0], Asrc, t + 1, 128)
      BAR(); MFMA16(ra, bq, 1); BAR();
    }
    // ph2: slot0 (ks1,mh0) | stage A1.mh1(t+1)
    {
      bf16x8 ra[4];
      RD_A4(ra, 0, 1, 0) RD_B4(bq, 0, 1)
      STAGE1(&As[1][0], Asrc, t + 1, 64) STAGE1(&As[1][0], Asrc, t + 1, 192)
      BAR(); MFMA16(ra, bq, 0); BAR();
    }
    // ph3: slot0 (ks1,mh1) | stage B0.h0(t+2) | VMCNT(4) post-MFMA
    {
      bf16x8 ra[4];
      RD_A4(ra, 0, 1, 1)
      if (t + 2 < NT) { STAGE1(&Bs[0][0], Bsrc, t + 2, 0) STAGE1(&Bs[0][0], Bsrc, t + 2, 64) }
      BAR(); MFMA16(ra, bq, 1);
      if (t + 2 < NT) { VMCNT(4); } else { VMCNT(0); }
      BAR();
    }
    // ph4: slot1 (ks0,mh0) | stage B0.h1(t+2) | VMCNT(4) post-MFMA
    {
      bf16x8 ra[4];
      RD_A4(ra, 1, 0, 0) RD_B4(bq, 1, 0)
      if (t + 2 < NT) { STAGE1(&Bs[0][0], Bsrc, t + 2, 128) STAGE1(&Bs[0][0], Bsrc, t + 2, 192) }
      BAR(); MFMA16(ra, bq, 0);
      if (t + 2 < NT) { VMCNT(4); } else { VMCNT(0); }
      BAR();
    }
    // ph5: slot1 (ks0,mh1) | stage A0.mh0(t+2)
    {
      bf16x8 ra[4];
      RD_A4(ra, 1, 0, 1)
      if (t + 2 < NT) { STAGE1(&As[0][0], Asrc, t + 2, 0) STAGE1(&As[0][0], Asrc, t + 2, 128) }
      BAR(); MFMA16(ra, bq, 1); BAR();
    }
    // ph6: slot1 (ks1,mh0) | stage A0.mh1(t+2)
    {
      bf16x8 ra[4];
      RD_A4(ra, 1, 1, 0) RD_B4(bq, 1, 1)
      if (t + 2 < NT) { STAGE1(&As[0][0], Asrc, t + 2, 64) STAGE1(&As[0][0], Asrc, t + 2, 192) }
      BAR(); MFMA16(ra, bq, 0); BAR();
    }
    // ph7: slot1 (ks1,mh1) | stage B1.h0(t+3) | VMCNT(4) post-MFMA
    {
      bf16x8 ra[4];
      RD_A4(ra, 1, 1, 1)
      if (t + 2 < NT) { STAGE1(&Bs[1][0], Bsrc, t + 3, 0) STAGE1(&Bs[1][0], Bsrc, t + 3, 64) }
      BAR(); MFMA16(ra, bq, 1);
      if (t + 2 < NT) { VMCNT(4); } else { VMCNT(0); }
      BAR();
    }
  }

  // epilogue: non-temporal C stores (write-once stream must not evict the
  // bf16 input panels from L3 -- that eviction was the 12x HBM over-read)
  const int ncol = lane & 15;
  const int qrow = (lane >> 4) * 4;
  float bv[4];
#pragma unroll
  for (int ni = 0; ni < 4; ++ni)
    bv[ni] = bias[bn * BN + wn * 64 + ni * 16 + ncol];
#pragma unroll
  for (int mi = 0; mi < 8; ++mi)
#pragma unroll
    for (int ni = 0; ni < 4; ++ni) {
      const int gn = bn * BN + wn * 64 + ni * 16 + ncol;
#pragma unroll
      for (int r = 0; r < 4; ++r) {
        const int gm = bm * BM + wm * 128 + mi * 16 + qrow + r;
        __builtin_nontemporal_store(acc[mi][ni][r] + bv[ni],
                                    &C[(size_t)gm * OUTF + gn]);
      }
    }
}

// ---------------- fused fallback (no workspace requirement) ----------------

#define FBM 128
#define FBN 128

#define FMFMA_COMPUTE()                                                       \
  do {                                                                        \
    const int frr = lane & 15;                                                \
    const int fq4 = lane >> 4;                                                \
    _Pragma("unroll") for (int ks = 0; ks < 2; ++ks) {                        \
      bf16x8 fa[4], fb[4];                                                    \
      const int kk = (((ks * 4 + fq4) ^ (frr & 7)) * 8);                      \
      _Pragma("unroll") for (int i = 0; i < 4; ++i) {                         \
        fa[i] = *(const bf16x8*)&Asf[(mwave + i * 16 + frr) * BK + kk];       \
        fb[i] = *(const bf16x8*)&Bsf[(nwave + i * 16 + frr) * BK + kk];       \
      }                                                                       \
      _Pragma("unroll") for (int mi = 0; mi < 4; ++mi)                        \
        _Pragma("unroll") for (int ni = 0; ni < 4; ++ni)                      \
          facc[mi][ni] = __builtin_amdgcn_mfma_f32_16x16x32_bf16(             \
              fa[mi], fb[ni], facc[mi][ni], 0, 0, 0);                         \
    }                                                                         \
  } while (0)

__global__ __launch_bounds__(256) void gemm_fused(const float* __restrict__ X,
                                                  const int* __restrict__ QW,
                                                  const float* __restrict__ scales,
                                                  const float* __restrict__ zeros,
                                                  const float* __restrict__ bias,
                                                  float* __restrict__ C) {
  __shared__ __align__(16) u16 Asf[FBM * BK];
  __shared__ __align__(16) u16 Bsf[FBN * BK];
  const int tid = threadIdx.x;
  const int lane = tid & 63;
  const int wid = tid >> 6;
  const int bm = blockIdx.y, bn = blockIdx.x;
  const int row = tid >> 1;
  const int half = tid & 1;
  const float* xr = X + (size_t)(bm * FBM + row) * INF + half * 32;
  const int* qr = QW + (size_t)(bn * FBN + row) * KB4 + half * 16;
  const float* srow = scales + (size_t)(bn * FBN + row) * NG;
  const float* zrow = zeros + (size_t)(bn * FBN + row) * NG;
  const int mwave = (wid >> 1) * 64;
  const int nwave = (wid & 1) * 64;
  f32x4 facc[4][4] = {};

  for (int kb = 0; kb < INF / BK; ++kb) {
    const int k0 = kb * BK;
    union { u16 t[32]; int4 v[4]; } ta, tb;
#pragma unroll
    for (int j = 0; j < 8; ++j) {
      const float4 f = *(const float4*)(xr + k0 + j * 4);
      ta.t[4 * j]     = f2bf(f.x);
      ta.t[4 * j + 1] = f2bf(f.y);
      ta.t[4 * j + 2] = f2bf(f.z);
      ta.t[4 * j + 3] = f2bf(f.w);
    }
    {
      const float s = srow[kb >> 1];
      const float zs = -zrow[kb >> 1] * s;
#pragma unroll
      for (int j = 0; j < 4; ++j) {
        const int4 q = *(const int4*)(qr + kb * 32 + j * 4);
        const int qq[4] = {q.x, q.y, q.z, q.w};
#pragma unroll
        for (int u = 0; u < 4; ++u) {
          tb.t[8 * j + 2 * u]     = f2bf(fmaf((float)(qq[u] & 15), s, zs));
          tb.t[8 * j + 2 * u + 1] = f2bf(fmaf((float)((qq[u] >> 4) & 15), s, zs));
        }
      }
    }
    __syncthreads();
#pragma unroll
    for (int j = 0; j < 4; ++j) {
      *(int4*)&Asf[row * BK + (((half * 4 + j) ^ (row & 7)) * 8)] = ta.v[j];
      *(int4*)&Bsf[row * BK + (((half * 4 + j) ^ (row & 7)) * 8)] = tb.v[j];
    }
    __syncthreads();
    FMFMA_COMPUTE();
  }
  {
    const int ncol = lane & 15;
    const int qrow = (lane >> 4) * 4;
#pragma unroll
    for (int mi = 0; mi < 4; ++mi)
#pragma unroll
      for (int ni = 0; ni < 4; ++ni) {
        const int gn = bn * FBN + nwave + ni * 16 + ncol;
        const float bvv = bias[gn];
#pragma unroll
        for (int r = 0; r < 4; ++r) {
          const int gm = bm * FBM + mwave + mi * 16 + qrow + r;
          C[(size_t)gm * OUTF + gn] = facc[mi][ni][r] + bvv;
        }
      }
  }
}

// ---------------- launch ----------------

extern "C" void kernel_launch(void* const* d_in, const int* in_sizes, int n_in,
                              void* d_out, int out_size, void* d_ws, size_t ws_size,
                              hipStream_t stream) {
  const float* x = (const float*)d_in[0];
  const int* qw = (const int*)d_in[1];
  const float* scales = (const float*)d_in[2];
  const float* zeros = (const float*)d_in[3];
  const float* bias = (const float*)d_in[4];
  float* out = (float*)d_out;

  const size_t needW = (size_t)OUTF * INF * sizeof(u16);  // 90,177,536 B
  const size_t needX = (size_t)TOK * INF * sizeof(u16);   // 67,108,864 B

  if (ws_size >= needW + needX) {
    u16* Wb = (u16*)d_ws;
    u16* Xb = (u16*)((char*)d_ws + needW);
    prep<<<PREPBLK, 256, 0, stream>>>(x, qw, scales, zeros, Xb, Wb);
    gemm_pre512<<<dim3(NWG), 512, 0, stream>>>(Xb, Wb, bias, out);
  } else {
    gemm_fused<<<dim3(OUTF / FBN, TOK / FBM), 256, 0, stream>>>(x, qw, scales, zeros, bias, out);
  }
}